// Round 1
// baseline (24259.622 us; speedup 1.0000x reference)
//
#include <hip/hip_runtime.h>
#include <math.h>

#define EMBED 768
#define NPATCH 1568
#define BB 2
#define MROWS (BB * NPATCH)   // 3136
#define HEADS 8
#define HDIM 96
#define MLPH 3072
#define DEPTH 12

// gemm epilogue flags
#define F_BIAS 1
#define F_GELU 2
#define F_RES  4
#define F_POS  8

// ---------------------------------------------------------------------------
// im2col for tubelet conv: kernel == stride == (2,16,16), x [2,3,16,224,224]
// col[row][k], row = b*1568 + n, k = ci*512 + kd*256 + kh*16 + kw
// ---------------------------------------------------------------------------
__global__ __launch_bounds__(256) void vit_im2col(const float* __restrict__ x,
                                                  float* __restrict__ col) {
  int idx = blockIdx.x * 256 + threadIdx.x;
  const int total = MROWS * (1536 / 4);
  if (idx >= total) return;
  int k4  = idx % (1536 / 4);
  int row = idx / (1536 / 4);
  int k = k4 * 4;
  int b = row / NPATCH, n = row % NPATCH;
  int dz = n / 196; int rem = n - dz * 196; int hy = rem / 14; int wx = rem - hy * 14;
  int ci = k >> 9; int kr = k & 511; int kd = kr >> 8; int kr2 = kr & 255;
  int kh = kr2 >> 4; int kw = kr2 & 15;
  const float* src = x + ((((size_t)b * 3 + ci) * 16 + (dz * 2 + kd)) * 224 +
                          (hy * 16 + kh)) * 224 + (wx * 16 + kw);
  *(float4*)(col + (size_t)row * 1536 + k) = *(const float4*)src;
}

// ---------------------------------------------------------------------------
// positional encoding value, matches numpy float64 table cast to fp32
// ---------------------------------------------------------------------------
__device__ inline float pos_embed_val(int n, int c) {
  double e = (double)(2 * (c >> 1)) / 768.0;
  double denom = pow(10000.0, e);
  double ang = (double)n / denom;
  return (float)((c & 1) ? cos(ang) : sin(ang));
}

// ---------------------------------------------------------------------------
// fp32 tiled GEMM: C[Mr][Nout] = A[Mr][K] * W[Nout][K]^T (+bias)(+gelu)(+pos)(+res)
// block 256 threads, 128x128 tile, BK=8, 8x8 per-thread microtile
// Nout and K must be multiples of 128 / 8 respectively (true for all calls)
// ---------------------------------------------------------------------------
template <int FLAGS>
__global__ __launch_bounds__(256) void vit_gemm(const float* __restrict__ A,
                                                const float* __restrict__ W,
                                                const float* __restrict__ bias,
                                                float* __restrict__ C,
                                                const float* __restrict__ Res,
                                                int Mr, int Nout, int K) {
  __shared__ float As[8][132];
  __shared__ float Ws[8][132];
  const int tid = threadIdx.x;
  const int m0 = blockIdx.y * 128;
  const int n0 = blockIdx.x * 128;
  const int tx = tid & 15, ty = tid >> 4;
  const int lr = tid >> 1;          // 0..127 tile row
  const int lq = (tid & 1) * 4;     // k sub-offset 0/4
  float acc[8][8];
#pragma unroll
  for (int i = 0; i < 8; i++)
#pragma unroll
    for (int j = 0; j < 8; j++) acc[i][j] = 0.f;

  const int arow = m0 + lr;
  const float* Aptr = A + (size_t)arow * K + lq;
  const float* Wptr = W + (size_t)(n0 + lr) * K + lq;

  for (int k0 = 0; k0 < K; k0 += 8) {
    float4 av = make_float4(0.f, 0.f, 0.f, 0.f);
    if (arow < Mr) av = *(const float4*)(Aptr + k0);
    float4 wv = *(const float4*)(Wptr + k0);
    As[lq + 0][lr] = av.x; As[lq + 1][lr] = av.y;
    As[lq + 2][lr] = av.z; As[lq + 3][lr] = av.w;
    Ws[lq + 0][lr] = wv.x; Ws[lq + 1][lr] = wv.y;
    Ws[lq + 2][lr] = wv.z; Ws[lq + 3][lr] = wv.w;
    __syncthreads();
#pragma unroll
    for (int kk = 0; kk < 8; kk++) {
      float4 a0 = *(const float4*)&As[kk][ty * 8];
      float4 a1 = *(const float4*)&As[kk][ty * 8 + 4];
      float4 b0 = *(const float4*)&Ws[kk][tx * 8];
      float4 b1 = *(const float4*)&Ws[kk][tx * 8 + 4];
      float ar[8] = {a0.x, a0.y, a0.z, a0.w, a1.x, a1.y, a1.z, a1.w};
      float br[8] = {b0.x, b0.y, b0.z, b0.w, b1.x, b1.y, b1.z, b1.w};
#pragma unroll
      for (int i = 0; i < 8; i++)
#pragma unroll
        for (int j = 0; j < 8; j++) acc[i][j] = fmaf(ar[i], br[j], acc[i][j]);
    }
    __syncthreads();
  }

#pragma unroll
  for (int i = 0; i < 8; i++) {
    int row = m0 + ty * 8 + i;
    if (row >= Mr) continue;
#pragma unroll
    for (int j = 0; j < 8; j++) {
      int col = n0 + tx * 8 + j;
      float v = acc[i][j];
      if (FLAGS & F_BIAS) v += bias[col];
      if (FLAGS & F_GELU) v = 0.5f * v * (1.f + erff(v * 0.70710678118654752f));
      if (FLAGS & F_POS)  v += pos_embed_val(row % NPATCH, col);
      if (FLAGS & F_RES)  v += Res[(size_t)row * Nout + col];
      C[(size_t)row * Nout + col] = v;
    }
  }
}

// ---------------------------------------------------------------------------
// LayerNorm over last dim (768). One block per row.
// ---------------------------------------------------------------------------
__global__ __launch_bounds__(256) void vit_ln(const float* __restrict__ X,
                                              float* __restrict__ Y,
                                              const float* __restrict__ scale,
                                              const float* __restrict__ bias) {
  const int row = blockIdx.x;
  const float* x = X + (size_t)row * EMBED;
  const int t = threadIdx.x;
  float v0 = x[t], v1 = x[t + 256], v2 = x[t + 512];
  float s = v0 + v1 + v2;
  float s2 = v0 * v0 + v1 * v1 + v2 * v2;
#pragma unroll
  for (int off = 32; off > 0; off >>= 1) {
    s += __shfl_down(s, off);
    s2 += __shfl_down(s2, off);
  }
  __shared__ float red[8];
  __shared__ float stats[2];
  int wid = t >> 6, lane = t & 63;
  if (lane == 0) { red[wid] = s; red[4 + wid] = s2; }
  __syncthreads();
  if (t == 0) {
    float S = red[0] + red[1] + red[2] + red[3];
    float S2 = red[4] + red[5] + red[6] + red[7];
    float mean = S * (1.f / 768.f);
    float var = S2 * (1.f / 768.f) - mean * mean;
    stats[0] = mean;
    stats[1] = rsqrtf(var + 1e-5f);
  }
  __syncthreads();
  float mean = stats[0], rstd = stats[1];
  float* y = Y + (size_t)row * EMBED;
  y[t]       = (v0 - mean) * rstd * scale[t]       + bias[t];
  y[t + 256] = (v1 - mean) * rstd * scale[t + 256] + bias[t + 256];
  y[t + 512] = (v2 - mean) * rstd * scale[t + 512] + bias[t + 512];
}

// ---------------------------------------------------------------------------
// Flash attention, fp32, no 1/sqrt(d) scale (per reference!).
// qkv layout: [b*N + n][3*768], q at +0, k at +768, v at +1536, head h at h*96.
// grid: (98 q-tiles of 16, 16 b*h). block 256.
// output O[b*N+n][h*96+j]  (== reshape(B,N,768))
// ---------------------------------------------------------------------------
#define TQ 16
#define TK 32
__global__ __launch_bounds__(256) void vit_attn(const float* __restrict__ qkv,
                                                float* __restrict__ O) {
  __shared__ float Qs[TQ][100];
  __shared__ float Ks[TK][100];
  __shared__ float Vs[TK][100];
  __shared__ float Ss[TQ][33];
  __shared__ float m_s[TQ], l_s[TQ], al_s[TQ];
  const int tid = threadIdx.x;
  const int bh = blockIdx.y;
  const int b = bh >> 3, hh = bh & 7;
  const int q0 = blockIdx.x * TQ;
  const size_t base = (size_t)b * NPATCH * 2304 + (size_t)hh * 96;

  for (int idx = tid; idx < TQ * 24; idx += 256) {
    int r = idx / 24, j4 = idx % 24;
    *(float4*)&Qs[r][j4 * 4] =
        *(const float4*)(qkv + base + (size_t)(q0 + r) * 2304 + j4 * 4);
  }
  if (tid < TQ) { m_s[tid] = -INFINITY; l_s[tid] = 0.f; }

  const int r = tid & 15, g = tid >> 4;
  const int j0 = g * 6;
  float acc[6] = {0.f, 0.f, 0.f, 0.f, 0.f, 0.f};

  for (int kt = 0; kt < NPATCH; kt += TK) {
    __syncthreads();  // previous tile's consumers done (also covers Qs stores)
    for (int idx = tid; idx < TK * 24; idx += 256) {
      int c = idx / 24, j4 = idx % 24;
      *(float4*)&Ks[c][j4 * 4] =
          *(const float4*)(qkv + base + 768 + (size_t)(kt + c) * 2304 + j4 * 4);
      *(float4*)&Vs[c][j4 * 4] =
          *(const float4*)(qkv + base + 1536 + (size_t)(kt + c) * 2304 + j4 * 4);
    }
    __syncthreads();
    // scores: each thread 2 dot products
    {
      int c0 = g * 2;
#pragma unroll
      for (int cc = 0; cc < 2; cc++) {
        int c = c0 + cc;
        float4 s4 = make_float4(0.f, 0.f, 0.f, 0.f);
#pragma unroll
        for (int k4 = 0; k4 < 24; k4++) {
          float4 qa = *(const float4*)&Qs[r][k4 * 4];
          float4 kb = *(const float4*)&Ks[c][k4 * 4];
          s4.x = fmaf(qa.x, kb.x, s4.x);
          s4.y = fmaf(qa.y, kb.y, s4.y);
          s4.z = fmaf(qa.z, kb.z, s4.z);
          s4.w = fmaf(qa.w, kb.w, s4.w);
        }
        Ss[r][c] = (s4.x + s4.y) + (s4.z + s4.w);
      }
    }
    __syncthreads();
    // online softmax bookkeeping, one thread per row
    if (tid < TQ) {
      float mold = m_s[tid], mnew = mold;
#pragma unroll
      for (int c = 0; c < TK; c++) mnew = fmaxf(mnew, Ss[tid][c]);
      float alpha = expf(mold - mnew);
      float rs = 0.f;
#pragma unroll
      for (int c = 0; c < TK; c++) {
        float p = expf(Ss[tid][c] - mnew);
        Ss[tid][c] = p;
        rs += p;
      }
      l_s[tid] = l_s[tid] * alpha + rs;
      m_s[tid] = mnew;
      al_s[tid] = alpha;
    }
    __syncthreads();
    // O += P * V
    float alpha = al_s[r];
#pragma unroll
    for (int jj = 0; jj < 6; jj++) acc[jj] *= alpha;
#pragma unroll
    for (int c = 0; c < TK; c++) {
      float p = Ss[r][c];
      float2 v0 = *(const float2*)&Vs[c][j0];
      float2 v1 = *(const float2*)&Vs[c][j0 + 2];
      float2 v2 = *(const float2*)&Vs[c][j0 + 4];
      acc[0] = fmaf(p, v0.x, acc[0]);
      acc[1] = fmaf(p, v0.y, acc[1]);
      acc[2] = fmaf(p, v1.x, acc[2]);
      acc[3] = fmaf(p, v1.y, acc[3]);
      acc[4] = fmaf(p, v2.x, acc[4]);
      acc[5] = fmaf(p, v2.y, acc[5]);
    }
  }
  float rl = 1.f / l_s[r];
  float* op = O + (size_t)(b * NPATCH + q0 + r) * EMBED + hh * 96 + j0;
#pragma unroll
  for (int jj = 0; jj < 6; jj++) op[jj] = acc[jj] * rl;
}

// ---------------------------------------------------------------------------
// mean over patches: pooled[b][c] = mean_n h[b][n][c]
// ---------------------------------------------------------------------------
__global__ __launch_bounds__(256) void vit_colmean(const float* __restrict__ h,
                                                   float* __restrict__ pooled) {
  int c = blockIdx.x * 256 + threadIdx.x;  // grid.x = 3
  int b = blockIdx.y;
  const float* p = h + (size_t)b * NPATCH * EMBED + c;
  float s = 0.f;
  for (int n = 0; n < NPATCH; n++) s += p[(size_t)n * EMBED];
  pooled[b * EMBED + c] = s * (1.f / (float)NPATCH);
}

// ---------------------------------------------------------------------------
// classifier head: out[b][cls] = pooled[b] . head_w[cls] + head_b[cls]
// one wave per output, 500 blocks x 4 waves = 2000 outputs
// ---------------------------------------------------------------------------
__global__ __launch_bounds__(256) void vit_head(const float* __restrict__ pooled,
                                                const float* __restrict__ hw,
                                                const float* __restrict__ hb,
                                                float* __restrict__ out) {
  int gw = (blockIdx.x * 256 + threadIdx.x) >> 6;
  int lane = threadIdx.x & 63;
  if (gw >= 2000) return;
  int b = gw / 1000, cls = gw % 1000;
  const float* p = pooled + b * EMBED;
  const float* w = hw + (size_t)cls * EMBED;
  float s = 0.f;
  for (int j = lane; j < EMBED; j += 64) s = fmaf(p[j], w[j], s);
#pragma unroll
  for (int off = 32; off > 0; off >>= 1) s += __shfl_down(s, off);
  if (lane == 0) out[gw] = s + hb[cls];
}

// ---------------------------------------------------------------------------
extern "C" void kernel_launch(void* const* d_in, const int* in_sizes, int n_in,
                              void* d_out, int out_size, void* d_ws, size_t ws_size,
                              hipStream_t stream) {
  const float* x      = (const float*)d_in[0];
  const float* conv_w = (const float*)d_in[1];
  const float* conv_b = (const float*)d_in[2];
  const float* n1s    = (const float*)d_in[3];
  const float* n1b    = (const float*)d_in[4];
  const float* qkv_w  = (const float*)d_in[5];
  const float* out_w  = (const float*)d_in[6];
  const float* out_b  = (const float*)d_in[7];
  const float* n2s    = (const float*)d_in[8];
  const float* n2b    = (const float*)d_in[9];
  const float* fc1_w  = (const float*)d_in[10];
  const float* fc1_b  = (const float*)d_in[11];
  const float* fc2_w  = (const float*)d_in[12];
  const float* fc2_b  = (const float*)d_in[13];
  const float* fns    = (const float*)d_in[14];
  const float* fnb    = (const float*)d_in[15];
  const float* head_w = (const float*)d_in[16];
  const float* head_b = (const float*)d_in[17];
  float* out = (float*)d_out;

  float* h   = (float*)d_ws;                       // [M][768]
  float* y   = h + (size_t)MROWS * EMBED;          // [M][768]  (LN out; also attn out)
  float* big = y + (size_t)MROWS * EMBED;          // [M][3072] (im2col / qkv / mlp1)
  float* pooled  = big + (size_t)MROWS * MLPH;     // [2][768]
  float* pooled2 = pooled + BB * EMBED;            // [2][768]

  // patch embed: im2col -> GEMM(+bias+pos) -> h
  vit_im2col<<<(MROWS * 384 + 255) / 256, 256, 0, stream>>>(x, big);
  vit_gemm<F_BIAS | F_POS><<<dim3(EMBED / 128, (MROWS + 127) / 128), 256, 0, stream>>>(
      big, conv_w, conv_b, h, nullptr, MROWS, EMBED, 1536);

  for (int l = 0; l < DEPTH; l++) {
    vit_ln<<<MROWS, 256, 0, stream>>>(h, y, n1s + l * EMBED, n1b + l * EMBED);
    vit_gemm<0><<<dim3(2304 / 128, (MROWS + 127) / 128), 256, 0, stream>>>(
        y, qkv_w + (size_t)l * 2304 * EMBED, nullptr, big, nullptr, MROWS, 2304, EMBED);
    vit_attn<<<dim3(NPATCH / TQ, BB * HEADS), 256, 0, stream>>>(big, y);
    vit_gemm<F_BIAS | F_RES><<<dim3(EMBED / 128, (MROWS + 127) / 128), 256, 0, stream>>>(
        y, out_w + (size_t)l * EMBED * EMBED, out_b + l * EMBED, h, h, MROWS, EMBED, EMBED);
    vit_ln<<<MROWS, 256, 0, stream>>>(h, y, n2s + l * EMBED, n2b + l * EMBED);
    vit_gemm<F_BIAS | F_GELU><<<dim3(MLPH / 128, (MROWS + 127) / 128), 256, 0, stream>>>(
        y, fc1_w + (size_t)l * MLPH * EMBED, fc1_b + l * MLPH, big, nullptr, MROWS, MLPH, EMBED);
    vit_gemm<F_BIAS | F_RES><<<dim3(EMBED / 128, (MROWS + 127) / 128), 256, 0, stream>>>(
        big, fc2_w + (size_t)l * EMBED * MLPH, fc2_b + l * EMBED, h, h, MROWS, EMBED, MLPH);
  }

  vit_colmean<<<dim3(3, BB), 256, 0, stream>>>(h, pooled);
  vit_ln<<<BB, 256, 0, stream>>>(pooled, pooled2, fns, fnb);
  vit_head<<<500, 256, 0, stream>>>(pooled2, head_w, head_b, out);
}

// Round 2
// 4315.314 us; speedup vs baseline: 5.6218x; 5.6218x over previous
//
#include <hip/hip_runtime.h>
#include <math.h>

#define EMBED 768
#define NPATCH 1568
#define BB 2
#define MROWS (BB * NPATCH)   // 3136
#define HEADS 8
#define MLPH 3072
#define DEPTH 12

#define F_BIAS 1
#define F_GELU 2
#define F_RES  4
#define F_POS  8

typedef unsigned short u16;
typedef __bf16 bf16x8 __attribute__((ext_vector_type(8)));
typedef float floatx4 __attribute__((ext_vector_type(4)));
typedef unsigned int u32x4 __attribute__((ext_vector_type(4)));   // 16B, 16B-aligned
typedef unsigned short u16x4 __attribute__((ext_vector_type(4))); // 8B

__device__ inline u16 f2bf(float f) {
  union { float f; unsigned int u; } v; v.f = f;
  unsigned int u = v.u;
  u += 0x7fffu + ((u >> 16) & 1u);   // RNE
  return (u16)(u >> 16);
}
__device__ inline void st_out(float* p, float v) { *p = v; }
__device__ inline void st_out(u16* p, float v) { *p = f2bf(v); }

// ---------------------------------------------------------------------------
// fp32 -> bf16 cast (4 elements/thread)
// ---------------------------------------------------------------------------
__global__ __launch_bounds__(256) void castw(const float* __restrict__ src,
                                             u16* __restrict__ dst, int n4) {
  int i = blockIdx.x * 256 + threadIdx.x;
  if (i >= n4) return;
  float4 v = ((const float4*)src)[i];
  u16x4 o; o.x = f2bf(v.x); o.y = f2bf(v.y); o.z = f2bf(v.z); o.w = f2bf(v.w);
  ((u16x4*)dst)[i] = o;
}

// ---------------------------------------------------------------------------
// im2col for tubelet conv (k==stride==(2,16,16)), bf16 output
// ---------------------------------------------------------------------------
__global__ __launch_bounds__(256) void vit_im2col(const float* __restrict__ x,
                                                  u16* __restrict__ col) {
  int idx = blockIdx.x * 256 + threadIdx.x;
  const int total = MROWS * 384;
  if (idx >= total) return;
  int k4 = idx % 384, row = idx / 384;
  int k = k4 * 4;
  int b = row / NPATCH, n = row % NPATCH;
  int dz = n / 196; int rem = n - dz * 196; int hy = rem / 14; int wx = rem - hy * 14;
  int ci = k >> 9; int kr = k & 511; int kd = kr >> 8; int kr2 = kr & 255;
  int kh = kr2 >> 4; int kw = kr2 & 15;
  const float* src = x + ((((size_t)b * 3 + ci) * 16 + (dz * 2 + kd)) * 224 +
                          (hy * 16 + kh)) * 224 + (wx * 16 + kw);
  float4 v = *(const float4*)src;
  u16x4 o; o.x = f2bf(v.x); o.y = f2bf(v.y); o.z = f2bf(v.z); o.w = f2bf(v.w);
  *(u16x4*)(col + (size_t)row * 1536 + k) = o;
}

__device__ inline float pos_embed_val(int n, int c) {
  double e = (double)(2 * (c >> 1)) / 768.0;
  double ang = (double)n / pow(10000.0, e);
  return (float)((c & 1) ? cos(ang) : sin(ang));
}

// ---------------------------------------------------------------------------
// MFMA bf16 GEMM: C[Mr][Nout] = A[Mr][K] * W[Nout][K]^T  (+epilogue)
// 128x128 tile, BK=32, 4 waves (2x2), each wave 64x64 = 4x4 frags of 16x16x32.
// LDS stride 56 u16 (112B): 16B-aligned b128 frag reads, 2-way banks (free).
// ---------------------------------------------------------------------------
template <int FLAGS, typename OT>
__global__ __launch_bounds__(256) void mfma_gemm(const u16* __restrict__ A,
                                                 const u16* __restrict__ W,
                                                 const float* __restrict__ bias,
                                                 OT* __restrict__ C,
                                                 const float* __restrict__ Res,
                                                 int Mr, int Nout, int K) {
  __shared__ u16 As[128 * 56] __attribute__((aligned(16)));
  __shared__ u16 Bs[128 * 56] __attribute__((aligned(16)));
  const int tid = threadIdx.x;
  const int m0 = blockIdx.y * 128, n0 = blockIdx.x * 128;
  const int lane = tid & 63, w = tid >> 6;
  const int wr = w >> 1, wc = w & 1;
  const int l15 = lane & 15, quad = lane >> 4;

  const int srow = tid >> 2, skoff = (tid & 3) * 8;
  int ar0 = m0 + srow;      if (ar0 > Mr - 1) ar0 = Mr - 1;
  int ar1 = m0 + 64 + srow; if (ar1 > Mr - 1) ar1 = Mr - 1;
  const u16* Ap0 = A + (size_t)ar0 * K + skoff;
  const u16* Ap1 = A + (size_t)ar1 * K + skoff;
  const u16* Bp0 = W + (size_t)(n0 + srow) * K + skoff;
  const u16* Bp1 = W + (size_t)(n0 + 64 + srow) * K + skoff;
  u16* Asw = As + srow * 56 + skoff;
  u16* Bsw = Bs + srow * 56 + skoff;

  floatx4 acc[4][4];
#pragma unroll
  for (int i = 0; i < 4; i++)
#pragma unroll
    for (int j = 0; j < 4; j++) acc[i][j] = (floatx4){0.f, 0.f, 0.f, 0.f};

  u32x4 ga0 = *(const u32x4*)Ap0, ga1 = *(const u32x4*)Ap1;
  u32x4 gb0 = *(const u32x4*)Bp0, gb1 = *(const u32x4*)Bp1;

  for (int k0 = 0; k0 < K; k0 += 32) {
    __syncthreads();
    *(u32x4*)Asw = ga0; *(u32x4*)(Asw + 64 * 56) = ga1;
    *(u32x4*)Bsw = gb0; *(u32x4*)(Bsw + 64 * 56) = gb1;
    __syncthreads();
    int kn = k0 + 32;
    if (kn < K) {   // prefetch next slab (overlaps MFMA below)
      ga0 = *(const u32x4*)(Ap0 + kn); ga1 = *(const u32x4*)(Ap1 + kn);
      gb0 = *(const u32x4*)(Bp0 + kn); gb1 = *(const u32x4*)(Bp1 + kn);
    }
    bf16x8 af[4], bfr[4];
#pragma unroll
    for (int i = 0; i < 4; i++)
      af[i] = *(const bf16x8*)(As + (wr * 64 + i * 16 + l15) * 56 + quad * 8);
#pragma unroll
    for (int j = 0; j < 4; j++)
      bfr[j] = *(const bf16x8*)(Bs + (wc * 64 + j * 16 + l15) * 56 + quad * 8);
#pragma unroll
    for (int i = 0; i < 4; i++)
#pragma unroll
      for (int j = 0; j < 4; j++)
        acc[i][j] = __builtin_amdgcn_mfma_f32_16x16x32_bf16(af[i], bfr[j], acc[i][j], 0, 0, 0);
  }

#pragma unroll
  for (int i = 0; i < 4; i++) {
#pragma unroll
    for (int j = 0; j < 4; j++) {
      int col = n0 + wc * 64 + j * 16 + l15;
#pragma unroll
      for (int r = 0; r < 4; r++) {
        int row = m0 + wr * 64 + i * 16 + quad * 4 + r;
        if (row >= Mr) continue;
        float v = acc[i][j][r];
        if (FLAGS & F_BIAS) v += bias[col];
        if (FLAGS & F_GELU) v = 0.5f * v * (1.f + erff(v * 0.70710678118654752f));
        if (FLAGS & F_POS)  v += pos_embed_val(row % NPATCH, col);
        if (FLAGS & F_RES)  v += Res[(size_t)row * Nout + col];
        st_out(C + (size_t)row * Nout + col, v);
      }
    }
  }
}

// ---------------------------------------------------------------------------
// LayerNorm over last dim (768), fp32 in, templated out
// ---------------------------------------------------------------------------
template <typename OT>
__global__ __launch_bounds__(256) void vit_ln(const float* __restrict__ X,
                                              OT* __restrict__ Y,
                                              const float* __restrict__ scale,
                                              const float* __restrict__ bias) {
  const int row = blockIdx.x;
  const float* x = X + (size_t)row * EMBED;
  const int t = threadIdx.x;
  float v0 = x[t], v1 = x[t + 256], v2 = x[t + 512];
  float s = v0 + v1 + v2;
  float s2 = v0 * v0 + v1 * v1 + v2 * v2;
#pragma unroll
  for (int off = 32; off > 0; off >>= 1) {
    s += __shfl_down(s, off);
    s2 += __shfl_down(s2, off);
  }
  __shared__ float red[8];
  __shared__ float stats[2];
  int wid = t >> 6, lane = t & 63;
  if (lane == 0) { red[wid] = s; red[4 + wid] = s2; }
  __syncthreads();
  if (t == 0) {
    float S = red[0] + red[1] + red[2] + red[3];
    float S2 = red[4] + red[5] + red[6] + red[7];
    float mean = S * (1.f / 768.f);
    float var = S2 * (1.f / 768.f) - mean * mean;
    stats[0] = mean; stats[1] = rsqrtf(var + 1e-5f);
  }
  __syncthreads();
  float mean = stats[0], rstd = stats[1];
  OT* y = Y + (size_t)row * EMBED;
  st_out(y + t,       (v0 - mean) * rstd * scale[t]       + bias[t]);
  st_out(y + t + 256, (v1 - mean) * rstd * scale[t + 256] + bias[t + 256]);
  st_out(y + t + 512, (v2 - mean) * rstd * scale[t + 512] + bias[t + 512]);
}

// ---------------------------------------------------------------------------
// V transpose: qkvb [3136][2304] bf16 (V at +1536) -> Vt [16][96][1568] bf16
// ---------------------------------------------------------------------------
__global__ __launch_bounds__(128) void vtrans(const u16* __restrict__ qkvb,
                                              u16* __restrict__ Vt) {
  __shared__ u16 T[32][48] __attribute__((aligned(16)));
  int bx = blockIdx.x, by = blockIdx.y, bh = blockIdx.z;
  int b = bh >> 3, h = bh & 7;
  int t = threadIdx.x;
  int r = t >> 2, c = (t & 3) * 8;
  int n = bx * 32 + r;
  const u16* src = qkvb + ((size_t)(b * NPATCH + n)) * 2304 + 1536 + h * 96 + by * 32 + c;
  *(u32x4*)&T[r][c] = *(const u32x4*)src;
  __syncthreads();
  u16 tmp[8];
#pragma unroll
  for (int j = 0; j < 8; j++) tmp[j] = T[c + j][r];
  u16* dst = Vt + (size_t)bh * 96 * NPATCH + (size_t)(by * 32 + r) * NPATCH + bx * 32 + c;
  *(u32x4*)dst = *(u32x4*)tmp;
}

// ---------------------------------------------------------------------------
// MFMA flash attention, NO 1/sqrt(d) scale (per reference).
// Block: 256 thr (4 waves), 64 q-rows/block (16/wave), K-tiles of 32.
// Q,K from qkvb [3136][2304] bf16; V from Vt [16][96][1568] bf16.
// Output O[3136][768] bf16.
// ---------------------------------------------------------------------------
__global__ __launch_bounds__(256) void vit_attn(const u16* __restrict__ qkvb,
                                                const u16* __restrict__ Vt,
                                                u16* __restrict__ O) {
  __shared__ u16 Ks[32 * 104] __attribute__((aligned(16)));   // [32 kcol][96+8 d]
  __shared__ u16 Vs[96 * 56]  __attribute__((aligned(16)));   // [96 d][32+24 k]
  __shared__ u16 Ps[4][16 * 56] __attribute__((aligned(16))); // per-wave [16 q][32+24 k]
  const int tid = threadIdx.x;
  const int w = tid >> 6, lane = tid & 63;
  const int l15 = lane & 15, quad = lane >> 4;
  const int bh = blockIdx.y, b = bh >> 3, hh = bh & 7;
  const int q0 = blockIdx.x * 64;
  const size_t qbase = (size_t)b * NPATCH * 2304 + (size_t)hh * 96;
  const size_t kbase = qbase + 768;
  const size_t vtb = (size_t)bh * 96 * NPATCH;

  // hoist Q A-frags straight from global (row clamped for ragged last tile)
  bf16x8 qf[3];
  {
    int gq = q0 + w * 16 + l15; if (gq > NPATCH - 1) gq = NPATCH - 1;
    const u16* qp = qkvb + qbase + (size_t)gq * 2304 + quad * 8;
    qf[0] = *(const bf16x8*)(qp);
    qf[1] = *(const bf16x8*)(qp + 32);
    qf[2] = *(const bf16x8*)(qp + 64);
  }

  floatx4 of[6];
#pragma unroll
  for (int dc = 0; dc < 6; dc++) of[dc] = (floatx4){0.f, 0.f, 0.f, 0.f};
  float m_r[4] = {-INFINITY, -INFINITY, -INFINITY, -INFINITY};
  float l_r[4] = {0.f, 0.f, 0.f, 0.f};
  u16* pw = &Ps[w][0];

  for (int kt = 0; kt < NPATCH; kt += 32) {
    __syncthreads();  // protect Ks/Vs from previous iteration's readers
    for (int idx = tid; idx < 384; idx += 256) {        // K tile 32x96
      int r = idx / 12, c8 = idx % 12;
      *(u32x4*)(Ks + r * 104 + c8 * 8) =
          *(const u32x4*)(qkvb + kbase + (size_t)(kt + r) * 2304 + c8 * 8);
    }
    for (int idx = tid; idx < 384; idx += 256) {        // V^T tile 96x32
      int d = idx >> 2, c8 = idx & 3;
      *(u32x4*)(Vs + d * 56 + c8 * 8) =
          *(const u32x4*)(Vt + vtb + (size_t)d * NPATCH + kt + c8 * 8);
    }
    __syncthreads();

    // S = Q K^T : two 16x16 frags (kcols 0-15, 16-31)
    floatx4 sf0 = (floatx4){0.f, 0.f, 0.f, 0.f};
    floatx4 sf1 = (floatx4){0.f, 0.f, 0.f, 0.f};
#pragma unroll
    for (int kc = 0; kc < 3; kc++) {
      bf16x8 kf0 = *(const bf16x8*)(Ks + l15 * 104 + kc * 32 + quad * 8);
      bf16x8 kf1 = *(const bf16x8*)(Ks + (16 + l15) * 104 + kc * 32 + quad * 8);
      sf0 = __builtin_amdgcn_mfma_f32_16x16x32_bf16(qf[kc], kf0, sf0, 0, 0, 0);
      sf1 = __builtin_amdgcn_mfma_f32_16x16x32_bf16(qf[kc], kf1, sf1, 0, 0, 0);
    }

    // online softmax (per row = quad*4+r; stats replicated across 16 lanes)
    float alpha[4], p0[4], p1[4];
#pragma unroll
    for (int r = 0; r < 4; r++) {
      float t = fmaxf(sf0[r], sf1[r]);
      t = fmaxf(t, __shfl_xor(t, 1));
      t = fmaxf(t, __shfl_xor(t, 2));
      t = fmaxf(t, __shfl_xor(t, 4));
      t = fmaxf(t, __shfl_xor(t, 8));
      float mnew = fmaxf(m_r[r], t);
      alpha[r] = __expf(m_r[r] - mnew);
      m_r[r] = mnew;
      p0[r] = __expf(sf0[r] - mnew);
      p1[r] = __expf(sf1[r] - mnew);
      float rs = p0[r] + p1[r];
      rs += __shfl_xor(rs, 1);
      rs += __shfl_xor(rs, 2);
      rs += __shfl_xor(rs, 4);
      rs += __shfl_xor(rs, 8);
      l_r[r] = l_r[r] * alpha[r] + rs;
    }
    // P -> wave-private LDS (C-layout write, A-layout read; DS ops in-order per wave)
#pragma unroll
    for (int r = 0; r < 4; r++) {
      pw[(quad * 4 + r) * 56 + l15] = f2bf(p0[r]);
      pw[(quad * 4 + r) * 56 + 16 + l15] = f2bf(p1[r]);
    }
    bf16x8 af = *(const bf16x8*)(pw + l15 * 56 + quad * 8);
#pragma unroll
    for (int dc = 0; dc < 6; dc++) {
      bf16x8 vf = *(const bf16x8*)(Vs + (dc * 16 + l15) * 56 + quad * 8);
      floatx4 o = of[dc];
#pragma unroll
      for (int r = 0; r < 4; r++) o[r] *= alpha[r];
      of[dc] = __builtin_amdgcn_mfma_f32_16x16x32_bf16(af, vf, o, 0, 0, 0);
    }
  }

  float inv_l[4];
#pragma unroll
  for (int r = 0; r < 4; r++) inv_l[r] = 1.f / l_r[r];
  const int gqb = q0 + w * 16 + quad * 4;
#pragma unroll
  for (int dc = 0; dc < 6; dc++) {
#pragma unroll
    for (int r = 0; r < 4; r++) {
      int gq = gqb + r;
      if (gq < NPATCH)
        O[(size_t)(b * NPATCH + gq) * EMBED + hh * 96 + dc * 16 + l15] =
            f2bf(of[dc][r] * inv_l[r]);
    }
  }
}

// ---------------------------------------------------------------------------
__global__ __launch_bounds__(256) void vit_colmean(const float* __restrict__ h,
                                                   float* __restrict__ pooled) {
  int c = blockIdx.x * 256 + threadIdx.x;
  int b = blockIdx.y;
  const float* p = h + (size_t)b * NPATCH * EMBED + c;
  float s = 0.f;
  for (int n = 0; n < NPATCH; n++) s += p[(size_t)n * EMBED];
  pooled[b * EMBED + c] = s * (1.f / (float)NPATCH);
}

__global__ __launch_bounds__(256) void vit_head(const float* __restrict__ pooled,
                                                const float* __restrict__ hw,
                                                const float* __restrict__ hb,
                                                float* __restrict__ out) {
  int gw = (blockIdx.x * 256 + threadIdx.x) >> 6;
  int lane = threadIdx.x & 63;
  if (gw >= 2000) return;
  int b = gw / 1000, cls = gw % 1000;
  const float* p = pooled + b * EMBED;
  const float* wv = hw + (size_t)cls * EMBED;
  float s = 0.f;
  for (int j = lane; j < EMBED; j += 64) s = fmaf(p[j], wv[j], s);
#pragma unroll
  for (int off = 32; off > 0; off >>= 1) s += __shfl_down(s, off);
  if (lane == 0) out[gw] = s + hb[cls];
}

// ---------------------------------------------------------------------------
extern "C" void kernel_launch(void* const* d_in, const int* in_sizes, int n_in,
                              void* d_out, int out_size, void* d_ws, size_t ws_size,
                              hipStream_t stream) {
  const float* x      = (const float*)d_in[0];
  const float* conv_w = (const float*)d_in[1];
  const float* conv_b = (const float*)d_in[2];
  const float* n1s    = (const float*)d_in[3];
  const float* n1b    = (const float*)d_in[4];
  const float* qkv_w  = (const float*)d_in[5];
  const float* out_w  = (const float*)d_in[6];
  const float* out_b  = (const float*)d_in[7];
  const float* n2s    = (const float*)d_in[8];
  const float* n2b    = (const float*)d_in[9];
  const float* fc1_w  = (const float*)d_in[10];
  const float* fc1_b  = (const float*)d_in[11];
  const float* fc2_w  = (const float*)d_in[12];
  const float* fc2_b  = (const float*)d_in[13];
  const float* fns    = (const float*)d_in[14];
  const float* fnb    = (const float*)d_in[15];
  const float* head_w = (const float*)d_in[16];
  const float* head_b = (const float*)d_in[17];
  float* out = (float*)d_out;

  char* ws = (char*)d_ws;
  float* h      = (float*)ws;                       // [3136][768] fp32   9,633,792 B
  u16*   qkvb   = (u16*)(ws + 9633792);             // [3136][2304] bf16 14,450,688 B
  u16*   regB   = (u16*)(ws + 24084480);            // 24,084,480 B region
  u16*   ybf    = regB;                             // [3136][768] bf16 (LN out / attn out)
  u16*   attnout= regB;
  u16*   mlpb   = regB + (size_t)MROWS * EMBED;     // [3136][3072] bf16
  u16*   im2c   = regB;                             // [3136][1536] bf16 (conv time only)
  u16*   Vt     = (u16*)(ws + 48168960);            // [16][96][1568] bf16 4,816,896 B
  u16*   wbuf   = (u16*)(ws + 52985856);            // 4,718,592 B weight cast buffer
  float* pooled = (float*)(ws + 57704448);
  float* pooled2= pooled + BB * EMBED;

  // patch embed
  vit_im2col<<<(MROWS * 384 + 255) / 256, 256, 0, stream>>>(x, im2c);
  castw<<<(1536 * 768 / 4 + 255) / 256, 256, 0, stream>>>(conv_w, wbuf, 1536 * 768 / 4);
  mfma_gemm<F_BIAS | F_POS, float><<<dim3(6, 25), 256, 0, stream>>>(
      im2c, wbuf, conv_b, h, nullptr, MROWS, 768, 1536);

  for (int l = 0; l < DEPTH; l++) {
    vit_ln<u16><<<MROWS, 256, 0, stream>>>(h, ybf, n1s + l * EMBED, n1b + l * EMBED);
    castw<<<(2304 * 768 / 4 + 255) / 256, 256, 0, stream>>>(
        qkv_w + (size_t)l * 2304 * 768, wbuf, 2304 * 768 / 4);
    mfma_gemm<0, u16><<<dim3(18, 25), 256, 0, stream>>>(
        ybf, wbuf, nullptr, qkvb, nullptr, MROWS, 2304, 768);
    vtrans<<<dim3(49, 3, 16), 128, 0, stream>>>(qkvb, Vt);
    vit_attn<<<dim3(25, 16), 256, 0, stream>>>(qkvb, Vt, attnout);
    castw<<<(768 * 768 / 4 + 255) / 256, 256, 0, stream>>>(
        out_w + (size_t)l * 768 * 768, wbuf, 768 * 768 / 4);
    mfma_gemm<F_BIAS | F_RES, float><<<dim3(6, 25), 256, 0, stream>>>(
        attnout, wbuf, out_b + l * EMBED, h, h, MROWS, 768, 768);
    vit_ln<u16><<<MROWS, 256, 0, stream>>>(h, ybf, n2s + l * EMBED, n2b + l * EMBED);
    castw<<<(3072 * 768 / 4 + 255) / 256, 256, 0, stream>>>(
        fc1_w + (size_t)l * 3072 * 768, wbuf, 3072 * 768 / 4);
    mfma_gemm<F_BIAS | F_GELU, u16><<<dim3(24, 25), 256, 0, stream>>>(
        ybf, wbuf, fc1_b + l * MLPH, mlpb, nullptr, MROWS, 3072, 768);
    castw<<<(768 * 3072 / 4 + 255) / 256, 256, 0, stream>>>(
        fc2_w + (size_t)l * 768 * 3072, wbuf, 768 * 3072 / 4);
    mfma_gemm<F_BIAS | F_RES, float><<<dim3(6, 25), 256, 0, stream>>>(
        mlpb, wbuf, fc2_b + l * EMBED, h, h, MROWS, 768, 3072);
  }

  vit_colmean<<<dim3(3, BB), 256, 0, stream>>>(h, pooled);
  vit_ln<float><<<BB, 256, 0, stream>>>(pooled, pooled2, fns, fnb);
  vit_head<<<500, 256, 0, stream>>>(pooled2, head_w, head_b, out);
}

// Round 3
// 3769.766 us; speedup vs baseline: 6.4353x; 1.1447x over previous
//
#include <hip/hip_runtime.h>
#include <math.h>

#define EMBED 768
#define NPATCH 1568
#define BB 2
#define MROWS (BB * NPATCH)   // 3136
#define HEADS 8
#define MLPH 3072
#define DEPTH 12

#define F_BIAS 1
#define F_GELU 2
#define F_RES  4
#define F_POS  8

typedef unsigned short u16;
typedef __bf16 bf16x8 __attribute__((ext_vector_type(8)));
typedef float floatx4 __attribute__((ext_vector_type(4)));
typedef unsigned int u32x4 __attribute__((ext_vector_type(4)));   // 16B, 16B-aligned
typedef unsigned short u16x4 __attribute__((ext_vector_type(4))); // 8B

__device__ inline u16 f2bf(float f) {
  union { float f; unsigned int u; } v; v.f = f;
  unsigned int u = v.u;
  u += 0x7fffu + ((u >> 16) & 1u);   // RNE
  return (u16)(u >> 16);
}
__device__ inline void st_out(float* p, float v) { *p = v; }
__device__ inline void st_out(u16* p, float v) { *p = f2bf(v); }

// ---------------------------------------------------------------------------
// fp32 -> bf16 cast (4 elements/thread)
// ---------------------------------------------------------------------------
__global__ __launch_bounds__(256) void castw(const float* __restrict__ src,
                                             u16* __restrict__ dst, int n4) {
  int i = blockIdx.x * 256 + threadIdx.x;
  if (i >= n4) return;
  float4 v = ((const float4*)src)[i];
  u16x4 o; o.x = f2bf(v.x); o.y = f2bf(v.y); o.z = f2bf(v.z); o.w = f2bf(v.w);
  ((u16x4*)dst)[i] = o;
}

// ---------------------------------------------------------------------------
// im2col for tubelet conv (k==stride==(2,16,16)), bf16 output
// ---------------------------------------------------------------------------
__global__ __launch_bounds__(256) void vit_im2col(const float* __restrict__ x,
                                                  u16* __restrict__ col) {
  int idx = blockIdx.x * 256 + threadIdx.x;
  const int total = MROWS * 384;
  if (idx >= total) return;
  int k4 = idx % 384, row = idx / 384;
  int k = k4 * 4;
  int b = row / NPATCH, n = row % NPATCH;
  int dz = n / 196; int rem = n - dz * 196; int hy = rem / 14; int wx = rem - hy * 14;
  int ci = k >> 9; int kr = k & 511; int kd = kr >> 8; int kr2 = kr & 255;
  int kh = kr2 >> 4; int kw = kr2 & 15;
  const float* src = x + ((((size_t)b * 3 + ci) * 16 + (dz * 2 + kd)) * 224 +
                          (hy * 16 + kh)) * 224 + (wx * 16 + kw);
  float4 v = *(const float4*)src;
  u16x4 o; o.x = f2bf(v.x); o.y = f2bf(v.y); o.z = f2bf(v.z); o.w = f2bf(v.w);
  *(u16x4*)(col + (size_t)row * 1536 + k) = o;
}

__device__ inline float pos_embed_val(int n, int c) {
  double e = (double)(2 * (c >> 1)) / 768.0;
  double ang = (double)n / pow(10000.0, e);
  return (float)((c & 1) ? cos(ang) : sin(ang));
}

// ---------------------------------------------------------------------------
// MFMA bf16 GEMM (fused epilogue): C[Mr][Nout] = A * W^T
// 128x128 tile, BK=32, 4 waves (2x2), wave = 64x64 = 4x4 frags of 16x16x32.
// Used for the wide GEMMs (qkv N=2304, fc1 N=3072) where grid >= 450 blocks.
// ---------------------------------------------------------------------------
template <int FLAGS, typename OT>
__global__ __launch_bounds__(256) void mfma_gemm(const u16* __restrict__ A,
                                                 const u16* __restrict__ W,
                                                 const float* __restrict__ bias,
                                                 OT* __restrict__ C,
                                                 const float* __restrict__ Res,
                                                 int Mr, int Nout, int K) {
  __shared__ u16 As[128 * 56] __attribute__((aligned(16)));
  __shared__ u16 Bs[128 * 56] __attribute__((aligned(16)));
  const int tid = threadIdx.x;
  const int m0 = blockIdx.y * 128, n0 = blockIdx.x * 128;
  const int lane = tid & 63, w = tid >> 6;
  const int wr = w >> 1, wc = w & 1;
  const int l15 = lane & 15, quad = lane >> 4;

  const int srow = tid >> 2, skoff = (tid & 3) * 8;
  int ar0 = m0 + srow;      if (ar0 > Mr - 1) ar0 = Mr - 1;
  int ar1 = m0 + 64 + srow; if (ar1 > Mr - 1) ar1 = Mr - 1;
  const u16* Ap0 = A + (size_t)ar0 * K + skoff;
  const u16* Ap1 = A + (size_t)ar1 * K + skoff;
  const u16* Bp0 = W + (size_t)(n0 + srow) * K + skoff;
  const u16* Bp1 = W + (size_t)(n0 + 64 + srow) * K + skoff;
  u16* Asw = As + srow * 56 + skoff;
  u16* Bsw = Bs + srow * 56 + skoff;

  floatx4 acc[4][4];
#pragma unroll
  for (int i = 0; i < 4; i++)
#pragma unroll
    for (int j = 0; j < 4; j++) acc[i][j] = (floatx4){0.f, 0.f, 0.f, 0.f};

  u32x4 ga0 = *(const u32x4*)Ap0, ga1 = *(const u32x4*)Ap1;
  u32x4 gb0 = *(const u32x4*)Bp0, gb1 = *(const u32x4*)Bp1;

  for (int k0 = 0; k0 < K; k0 += 32) {
    __syncthreads();
    *(u32x4*)Asw = ga0; *(u32x4*)(Asw + 64 * 56) = ga1;
    *(u32x4*)Bsw = gb0; *(u32x4*)(Bsw + 64 * 56) = gb1;
    __syncthreads();
    int kn = k0 + 32;
    if (kn < K) {
      ga0 = *(const u32x4*)(Ap0 + kn); ga1 = *(const u32x4*)(Ap1 + kn);
      gb0 = *(const u32x4*)(Bp0 + kn); gb1 = *(const u32x4*)(Bp1 + kn);
    }
    bf16x8 af[4], bfr[4];
#pragma unroll
    for (int i = 0; i < 4; i++)
      af[i] = *(const bf16x8*)(As + (wr * 64 + i * 16 + l15) * 56 + quad * 8);
#pragma unroll
    for (int j = 0; j < 4; j++)
      bfr[j] = *(const bf16x8*)(Bs + (wc * 64 + j * 16 + l15) * 56 + quad * 8);
#pragma unroll
    for (int i = 0; i < 4; i++)
#pragma unroll
      for (int j = 0; j < 4; j++)
        acc[i][j] = __builtin_amdgcn_mfma_f32_16x16x32_bf16(af[i], bfr[j], acc[i][j], 0, 0, 0);
  }

#pragma unroll
  for (int i = 0; i < 4; i++) {
#pragma unroll
    for (int j = 0; j < 4; j++) {
      int col = n0 + wc * 64 + j * 16 + l15;
#pragma unroll
      for (int r = 0; r < 4; r++) {
        int row = m0 + wr * 64 + i * 16 + quad * 4 + r;
        if (row >= Mr) continue;
        float v = acc[i][j][r];
        if (FLAGS & F_BIAS) v += bias[col];
        if (FLAGS & F_GELU) v = 0.5f * v * (1.f + erff(v * 0.70710678118654752f));
        if (FLAGS & F_RES)  v += Res[(size_t)row * Nout + col];
        st_out(C + (size_t)row * Nout + col, v);
      }
    }
  }
}

// ---------------------------------------------------------------------------
// Split-K MFMA GEMM for N=768 GEMMs (conv, out-proj, fc2): BM=128, BN=64.
// grid (Nout/64, ceil(M/128), S); z computes K-chunk [z*Kc, z*Kc+Kc) -> fp32
// partials P[z][M][Nout]. 600 blocks -> 2.3 blocks/CU (vs 150 before).
// ---------------------------------------------------------------------------
__global__ __launch_bounds__(256) void mfma_gemm_split(const u16* __restrict__ A,
                                                       const u16* __restrict__ W,
                                                       float* __restrict__ P,
                                                       int Mr, int Nout, int K, int Kc) {
  __shared__ u16 As[128 * 56] __attribute__((aligned(16)));
  __shared__ u16 Bs[64 * 56]  __attribute__((aligned(16)));
  const int tid = threadIdx.x;
  const int m0 = blockIdx.y * 128, n0 = blockIdx.x * 64;
  const int z = blockIdx.z;
  const int lane = tid & 63, w = tid >> 6;
  const int wr = w >> 1, wc = w & 1;            // wave = 64 rows x 32 cols
  const int l15 = lane & 15, quad = lane >> 4;

  const int srow = tid >> 2, skoff = (tid & 3) * 8;
  int ar0 = m0 + srow;      if (ar0 > Mr - 1) ar0 = Mr - 1;
  int ar1 = m0 + 64 + srow; if (ar1 > Mr - 1) ar1 = Mr - 1;
  const u16* Ap0 = A + (size_t)ar0 * K + skoff;
  const u16* Ap1 = A + (size_t)ar1 * K + skoff;
  const u16* Bp  = W + (size_t)(n0 + srow) * K + skoff;
  u16* Asw = As + srow * 56 + skoff;
  u16* Bsw = Bs + srow * 56 + skoff;

  floatx4 acc[4][2];
#pragma unroll
  for (int i = 0; i < 4; i++)
#pragma unroll
    for (int j = 0; j < 2; j++) acc[i][j] = (floatx4){0.f, 0.f, 0.f, 0.f};

  const int kb = z * Kc, ke = kb + Kc;
  u32x4 ga0 = *(const u32x4*)(Ap0 + kb), ga1 = *(const u32x4*)(Ap1 + kb);
  u32x4 gb = *(const u32x4*)(Bp + kb);

  for (int k0 = kb; k0 < ke; k0 += 32) {
    __syncthreads();
    *(u32x4*)Asw = ga0; *(u32x4*)(Asw + 64 * 56) = ga1;
    if (srow < 64) *(u32x4*)Bsw = gb;
    __syncthreads();
    int kn = k0 + 32;
    if (kn < ke) {
      ga0 = *(const u32x4*)(Ap0 + kn); ga1 = *(const u32x4*)(Ap1 + kn);
      gb = *(const u32x4*)(Bp + kn);
    }
    bf16x8 af[4], bfr[2];
#pragma unroll
    for (int i = 0; i < 4; i++)
      af[i] = *(const bf16x8*)(As + (wr * 64 + i * 16 + l15) * 56 + quad * 8);
#pragma unroll
    for (int j = 0; j < 2; j++)
      bfr[j] = *(const bf16x8*)(Bs + (wc * 32 + j * 16 + l15) * 56 + quad * 8);
#pragma unroll
    for (int i = 0; i < 4; i++)
#pragma unroll
      for (int j = 0; j < 2; j++)
        acc[i][j] = __builtin_amdgcn_mfma_f32_16x16x32_bf16(af[i], bfr[j], acc[i][j], 0, 0, 0);
  }

  float* Pz = P + (size_t)z * Mr * Nout;
#pragma unroll
  for (int i = 0; i < 4; i++) {
#pragma unroll
    for (int j = 0; j < 2; j++) {
      int col = n0 + wc * 32 + j * 16 + l15;
#pragma unroll
      for (int r = 0; r < 4; r++) {
        int row = m0 + wr * 64 + i * 16 + quad * 4 + r;
        if (row < Mr) Pz[(size_t)row * Nout + col] = acc[i][j][r];
      }
    }
  }
}

// ---------------------------------------------------------------------------
// split-K reduce + epilogue (bias / residual / pos-embed), float4 vectorized
// ---------------------------------------------------------------------------
template <int FLAGS>
__global__ __launch_bounds__(256) void reduce_split(const float* __restrict__ P, int S,
                                                    const float* __restrict__ bias,
                                                    const float* __restrict__ Res,
                                                    float* __restrict__ Out,
                                                    int n4, int Nout) {
  int i = blockIdx.x * 256 + threadIdx.x;
  if (i >= n4) return;
  const float4* p4 = (const float4*)P;
  float4 a = p4[i];
  for (int zz = 1; zz < S; zz++) {
    float4 b = p4[i + (size_t)zz * n4];
    a.x += b.x; a.y += b.y; a.z += b.z; a.w += b.w;
  }
  int col = (i * 4) % Nout;
  if (FLAGS & F_BIAS) {
    a.x += bias[col]; a.y += bias[col + 1]; a.z += bias[col + 2]; a.w += bias[col + 3];
  }
  if (FLAGS & F_POS) {
    int n = ((i * 4) / Nout) % NPATCH;
    a.x += pos_embed_val(n, col);
    a.y += pos_embed_val(n, col + 1);
    a.z += pos_embed_val(n, col + 2);
    a.w += pos_embed_val(n, col + 3);
  }
  if (FLAGS & F_RES) {
    float4 r4 = ((const float4*)Res)[i];
    a.x += r4.x; a.y += r4.y; a.z += r4.z; a.w += r4.w;
  }
  ((float4*)Out)[i] = a;
}

// ---------------------------------------------------------------------------
// LayerNorm over last dim (768), fp32 in, templated out
// ---------------------------------------------------------------------------
template <typename OT>
__global__ __launch_bounds__(256) void vit_ln(const float* __restrict__ X,
                                              OT* __restrict__ Y,
                                              const float* __restrict__ scale,
                                              const float* __restrict__ bias) {
  const int row = blockIdx.x;
  const float* x = X + (size_t)row * EMBED;
  const int t = threadIdx.x;
  float v0 = x[t], v1 = x[t + 256], v2 = x[t + 512];
  float s = v0 + v1 + v2;
  float s2 = v0 * v0 + v1 * v1 + v2 * v2;
#pragma unroll
  for (int off = 32; off > 0; off >>= 1) {
    s += __shfl_down(s, off);
    s2 += __shfl_down(s2, off);
  }
  __shared__ float red[8];
  __shared__ float stats[2];
  int wid = t >> 6, lane = t & 63;
  if (lane == 0) { red[wid] = s; red[4 + wid] = s2; }
  __syncthreads();
  if (t == 0) {
    float S = red[0] + red[1] + red[2] + red[3];
    float S2 = red[4] + red[5] + red[6] + red[7];
    float mean = S * (1.f / 768.f);
    float var = S2 * (1.f / 768.f) - mean * mean;
    stats[0] = mean; stats[1] = rsqrtf(var + 1e-5f);
  }
  __syncthreads();
  float mean = stats[0], rstd = stats[1];
  OT* y = Y + (size_t)row * EMBED;
  st_out(y + t,       (v0 - mean) * rstd * scale[t]       + bias[t]);
  st_out(y + t + 256, (v1 - mean) * rstd * scale[t + 256] + bias[t + 256]);
  st_out(y + t + 512, (v2 - mean) * rstd * scale[t + 512] + bias[t + 512]);
}

// ---------------------------------------------------------------------------
// V transpose: qkvb [3136][2304] bf16 (V at +1536) -> Vt [16][96][1568] bf16
// ---------------------------------------------------------------------------
__global__ __launch_bounds__(128) void vtrans(const u16* __restrict__ qkvb,
                                              u16* __restrict__ Vt) {
  __shared__ u16 T[32][48] __attribute__((aligned(16)));
  int bx = blockIdx.x, by = blockIdx.y, bh = blockIdx.z;
  int b = bh >> 3, h = bh & 7;
  int t = threadIdx.x;
  int r = t >> 2, c = (t & 3) * 8;
  int n = bx * 32 + r;
  const u16* src = qkvb + ((size_t)(b * NPATCH + n)) * 2304 + 1536 + h * 96 + by * 32 + c;
  *(u32x4*)&T[r][c] = *(const u32x4*)src;
  __syncthreads();
  u16 tmp[8];
#pragma unroll
  for (int j = 0; j < 8; j++) tmp[j] = T[c + j][r];
  u16* dst = Vt + (size_t)bh * 96 * NPATCH + (size_t)(by * 32 + r) * NPATCH + bx * 32 + c;
  *(u32x4*)dst = *(u32x4*)tmp;
}

// ---------------------------------------------------------------------------
// MFMA flash attention, NO 1/sqrt(d) scale (per reference).
// Block: 256 thr (4 waves), 64 q-rows/block (16/wave), K-tiles of 32.
// ---------------------------------------------------------------------------
__global__ __launch_bounds__(256) void vit_attn(const u16* __restrict__ qkvb,
                                                const u16* __restrict__ Vt,
                                                u16* __restrict__ O) {
  __shared__ u16 Ks[32 * 104] __attribute__((aligned(16)));
  __shared__ u16 Vs[96 * 56]  __attribute__((aligned(16)));
  __shared__ u16 Ps[4][16 * 56] __attribute__((aligned(16)));
  const int tid = threadIdx.x;
  const int w = tid >> 6, lane = tid & 63;
  const int l15 = lane & 15, quad = lane >> 4;
  const int bh = blockIdx.y, b = bh >> 3, hh = bh & 7;
  const int q0 = blockIdx.x * 64;
  const size_t qbase = (size_t)b * NPATCH * 2304 + (size_t)hh * 96;
  const size_t kbase = qbase + 768;
  const size_t vtb = (size_t)bh * 96 * NPATCH;

  bf16x8 qf[3];
  {
    int gq = q0 + w * 16 + l15; if (gq > NPATCH - 1) gq = NPATCH - 1;
    const u16* qp = qkvb + qbase + (size_t)gq * 2304 + quad * 8;
    qf[0] = *(const bf16x8*)(qp);
    qf[1] = *(const bf16x8*)(qp + 32);
    qf[2] = *(const bf16x8*)(qp + 64);
  }

  floatx4 of[6];
#pragma unroll
  for (int dc = 0; dc < 6; dc++) of[dc] = (floatx4){0.f, 0.f, 0.f, 0.f};
  float m_r[4] = {-INFINITY, -INFINITY, -INFINITY, -INFINITY};
  float l_r[4] = {0.f, 0.f, 0.f, 0.f};
  u16* pw = &Ps[w][0];

  for (int kt = 0; kt < NPATCH; kt += 32) {
    __syncthreads();
    for (int idx = tid; idx < 384; idx += 256) {
      int r = idx / 12, c8 = idx % 12;
      *(u32x4*)(Ks + r * 104 + c8 * 8) =
          *(const u32x4*)(qkvb + kbase + (size_t)(kt + r) * 2304 + c8 * 8);
    }
    for (int idx = tid; idx < 384; idx += 256) {
      int d = idx >> 2, c8 = idx & 3;
      *(u32x4*)(Vs + d * 56 + c8 * 8) =
          *(const u32x4*)(Vt + vtb + (size_t)d * NPATCH + kt + c8 * 8);
    }
    __syncthreads();

    floatx4 sf0 = (floatx4){0.f, 0.f, 0.f, 0.f};
    floatx4 sf1 = (floatx4){0.f, 0.f, 0.f, 0.f};
#pragma unroll
    for (int kc = 0; kc < 3; kc++) {
      bf16x8 kf0 = *(const bf16x8*)(Ks + l15 * 104 + kc * 32 + quad * 8);
      bf16x8 kf1 = *(const bf16x8*)(Ks + (16 + l15) * 104 + kc * 32 + quad * 8);
      sf0 = __builtin_amdgcn_mfma_f32_16x16x32_bf16(qf[kc], kf0, sf0, 0, 0, 0);
      sf1 = __builtin_amdgcn_mfma_f32_16x16x32_bf16(qf[kc], kf1, sf1, 0, 0, 0);
    }

    float alpha[4], p0[4], p1[4];
#pragma unroll
    for (int r = 0; r < 4; r++) {
      float t = fmaxf(sf0[r], sf1[r]);
      t = fmaxf(t, __shfl_xor(t, 1));
      t = fmaxf(t, __shfl_xor(t, 2));
      t = fmaxf(t, __shfl_xor(t, 4));
      t = fmaxf(t, __shfl_xor(t, 8));
      float mnew = fmaxf(m_r[r], t);
      alpha[r] = __expf(m_r[r] - mnew);
      m_r[r] = mnew;
      p0[r] = __expf(sf0[r] - mnew);
      p1[r] = __expf(sf1[r] - mnew);
      float rs = p0[r] + p1[r];
      rs += __shfl_xor(rs, 1);
      rs += __shfl_xor(rs, 2);
      rs += __shfl_xor(rs, 4);
      rs += __shfl_xor(rs, 8);
      l_r[r] = l_r[r] * alpha[r] + rs;
    }
#pragma unroll
    for (int r = 0; r < 4; r++) {
      pw[(quad * 4 + r) * 56 + l15] = f2bf(p0[r]);
      pw[(quad * 4 + r) * 56 + 16 + l15] = f2bf(p1[r]);
    }
    bf16x8 af = *(const bf16x8*)(pw + l15 * 56 + quad * 8);
#pragma unroll
    for (int dc = 0; dc < 6; dc++) {
      bf16x8 vf = *(const bf16x8*)(Vs + (dc * 16 + l15) * 56 + quad * 8);
      floatx4 o = of[dc];
#pragma unroll
      for (int r = 0; r < 4; r++) o[r] *= alpha[r];
      of[dc] = __builtin_amdgcn_mfma_f32_16x16x32_bf16(af, vf, o, 0, 0, 0);
    }
  }

  float inv_l[4];
#pragma unroll
  for (int r = 0; r < 4; r++) inv_l[r] = 1.f / l_r[r];
  const int gqb = q0 + w * 16 + quad * 4;
#pragma unroll
  for (int dc = 0; dc < 6; dc++) {
#pragma unroll
    for (int r = 0; r < 4; r++) {
      int gq = gqb + r;
      if (gq < NPATCH)
        O[(size_t)(b * NPATCH + gq) * EMBED + hh * 96 + dc * 16 + l15] =
            f2bf(of[dc][r] * inv_l[r]);
    }
  }
}

// ---------------------------------------------------------------------------
__global__ __launch_bounds__(256) void vit_colmean(const float* __restrict__ h,
                                                   float* __restrict__ pooled) {
  int c = blockIdx.x * 256 + threadIdx.x;
  int b = blockIdx.y;
  const float* p = h + (size_t)b * NPATCH * EMBED + c;
  float s = 0.f;
  for (int n = 0; n < NPATCH; n++) s += p[(size_t)n * EMBED];
  pooled[b * EMBED + c] = s * (1.f / (float)NPATCH);
}

__global__ __launch_bounds__(256) void vit_head(const float* __restrict__ pooled,
                                                const float* __restrict__ hw,
                                                const float* __restrict__ hb,
                                                float* __restrict__ out) {
  int gw = (blockIdx.x * 256 + threadIdx.x) >> 6;
  int lane = threadIdx.x & 63;
  if (gw >= 2000) return;
  int b = gw / 1000, cls = gw % 1000;
  const float* p = pooled + b * EMBED;
  const float* wv = hw + (size_t)cls * EMBED;
  float s = 0.f;
  for (int j = lane; j < EMBED; j += 64) s = fmaf(p[j], wv[j], s);
#pragma unroll
  for (int off = 32; off > 0; off >>= 1) s += __shfl_down(s, off);
  if (lane == 0) out[gw] = s + hb[cls];
}

// ---------------------------------------------------------------------------
extern "C" void kernel_launch(void* const* d_in, const int* in_sizes, int n_in,
                              void* d_out, int out_size, void* d_ws, size_t ws_size,
                              hipStream_t stream) {
  const float* x      = (const float*)d_in[0];
  const float* conv_w = (const float*)d_in[1];
  const float* conv_b = (const float*)d_in[2];
  const float* n1s    = (const float*)d_in[3];
  const float* n1b    = (const float*)d_in[4];
  const float* qkv_w  = (const float*)d_in[5];
  const float* out_w  = (const float*)d_in[6];
  const float* out_b  = (const float*)d_in[7];
  const float* n2s    = (const float*)d_in[8];
  const float* n2b    = (const float*)d_in[9];
  const float* fc1_w  = (const float*)d_in[10];
  const float* fc1_b  = (const float*)d_in[11];
  const float* fc2_w  = (const float*)d_in[12];
  const float* fc2_b  = (const float*)d_in[13];
  const float* fns    = (const float*)d_in[14];
  const float* fnb    = (const float*)d_in[15];
  const float* head_w = (const float*)d_in[16];
  const float* head_b = (const float*)d_in[17];
  float* out = (float*)d_out;

  // layout (qkvb+Vt contiguous => split-K partial buffer aliases them):
  // h      [3136][768] fp32      @ 0          9,633,792 B
  // qkvb   [3136][2304] bf16     @ 9,633,792 14,450,688 B   \ P (2x3136x768 fp32
  // Vt     [16][96][1568] bf16   @24,084,480  4,816,896 B   /  = 19,267,584 B)
  // regB                         @28,901,376 24,084,480 B  (ybf/attnout/mlpb/im2c)
  // wbuf                         @52,985,856  4,718,592 B
  // pooled                       @57,704,448
  char* ws = (char*)d_ws;
  float* h      = (float*)ws;
  u16*   qkvb   = (u16*)(ws + 9633792);
  u16*   Vt     = (u16*)(ws + 24084480);
  float* P      = (float*)(ws + 9633792);          // split-K partials
  u16*   regB   = (u16*)(ws + 28901376);
  u16*   ybf    = regB;
  u16*   attnout= regB;
  u16*   im2c   = regB;
  u16*   mlpb   = regB + (size_t)MROWS * EMBED;
  u16*   wbuf   = (u16*)(ws + 52985856);
  float* pooled = (float*)(ws + 57704448);
  float* pooled2= pooled + BB * EMBED;

  const int n4 = MROWS * EMBED / 4;   // 602112 -> 2352 blocks for reduce

  // patch embed: im2col -> split-K GEMM -> reduce(+bias+pos)
  vit_im2col<<<(MROWS * 384 + 255) / 256, 256, 0, stream>>>(x, im2c);
  castw<<<(1536 * 768 / 4 + 255) / 256, 256, 0, stream>>>(conv_w, wbuf, 1536 * 768 / 4);
  mfma_gemm_split<<<dim3(12, 25, 2), 256, 0, stream>>>(im2c, wbuf, P, MROWS, 768, 1536, 768);
  reduce_split<F_BIAS | F_POS><<<(n4 + 255) / 256, 256, 0, stream>>>(
      P, 2, conv_b, nullptr, h, n4, 768);

  for (int l = 0; l < DEPTH; l++) {
    vit_ln<u16><<<MROWS, 256, 0, stream>>>(h, ybf, n1s + l * EMBED, n1b + l * EMBED);
    castw<<<(2304 * 768 / 4 + 255) / 256, 256, 0, stream>>>(
        qkv_w + (size_t)l * 2304 * 768, wbuf, 2304 * 768 / 4);
    mfma_gemm<0, u16><<<dim3(18, 25), 256, 0, stream>>>(
        ybf, wbuf, nullptr, qkvb, nullptr, MROWS, 2304, 768);
    vtrans<<<dim3(49, 3, 16), 128, 0, stream>>>(qkvb, Vt);
    vit_attn<<<dim3(25, 16), 256, 0, stream>>>(qkvb, Vt, attnout);
    // out-proj: split-K (qkvb/Vt dead from here; P aliases them)
    castw<<<(768 * 768 / 4 + 255) / 256, 256, 0, stream>>>(
        out_w + (size_t)l * 768 * 768, wbuf, 768 * 768 / 4);
    mfma_gemm_split<<<dim3(12, 25, 2), 256, 0, stream>>>(attnout, wbuf, P, MROWS, 768, 768, 384);
    reduce_split<F_BIAS | F_RES><<<(n4 + 255) / 256, 256, 0, stream>>>(
        P, 2, out_b + l * EMBED, h, h, n4, 768);
    vit_ln<u16><<<MROWS, 256, 0, stream>>>(h, ybf, n2s + l * EMBED, n2b + l * EMBED);
    castw<<<(3072 * 768 / 4 + 255) / 256, 256, 0, stream>>>(
        fc1_w + (size_t)l * 3072 * 768, wbuf, 3072 * 768 / 4);
    mfma_gemm<F_BIAS | F_GELU, u16><<<dim3(24, 25), 256, 0, stream>>>(
        ybf, wbuf, fc1_b + l * MLPH, mlpb, nullptr, MROWS, 3072, 768);
    castw<<<(768 * 3072 / 4 + 255) / 256, 256, 0, stream>>>(
        fc2_w + (size_t)l * 768 * 3072, wbuf, 768 * 3072 / 4);
    mfma_gemm_split<<<dim3(12, 25, 2), 256, 0, stream>>>(mlpb, wbuf, P, MROWS, 768, 3072, 1536);
    reduce_split<F_BIAS | F_RES><<<(n4 + 255) / 256, 256, 0, stream>>>(
        P, 2, fc2_b + l * EMBED, h, h, n4, 768);
  }

  vit_colmean<<<dim3(3, BB), 256, 0, stream>>>(h, pooled);
  vit_ln<float><<<BB, 256, 0, stream>>>(pooled, pooled2, fns, fnb);
  vit_head<<<500, 256, 0, stream>>>(pooled2, head_w, head_b, out);
}